// Round 7
// baseline (244.038 us; speedup 1.0000x reference)
//
#include <hip/hip_runtime.h>

// CenterLoss: feature [B=128, D=128, T=2048] f32, label [B*T] int32, centers [64,128] f32
// out: [1 + 64*128] f32 = (loss, difference)
//
// R1-R3: LDS float atomics (~180us). R5/R6: counting-sort gather, k_main ~60-70us,
// DS-pipe + barrier bound (2 blocks/CU didn't help -> shared LDS pipe).
// R7: one-hot MFMA GEMM. S[c,d] = sum_t onehot[c,t]*feat[d,t]:
//   A = feat (m=d, k=t): lane reads 8 contiguous t straight from GLOBAL (2x dwordx4),
//       converts f32->bf16 in regs. NO LDS staging, NO barriers in K-loop.
//   B = onehot (k=t, n=c): built in registers from LDS-broadcast labels.
//   ss computed from f32 values before conversion (exact path).
// bf16 error on diff ~ eps/sqrt(cnt) ~ 3e-5 << 7.3e-2 threshold.

#define NT 2048
#define NC 64

// ws float offsets
#define OFF_P     0          // [512 blocks][128 d][64 c] partial S (f32)
#define OFF_SSP   4194304    // [512] per-block sumsq
#define OFF_CNTP  4194816    // int [512 blocks][64 c]
#define OFF_CROSS 4227584    // [32]
#define OFF_CC    4227616    // [32]
#define OFF_SS    4227648    // [1]

typedef __attribute__((ext_vector_type(8))) short bf16x8;
typedef __attribute__((ext_vector_type(4))) float f32x4;

__device__ __forceinline__ unsigned short bf16rne(float f) {
    unsigned int u = __float_as_uint(f);
    return (unsigned short)((u + 0x7FFFu + ((u >> 16) & 1u)) >> 16);
}

__global__ __launch_bounds__(256) void k_main(const float* __restrict__ feat,
                                              const int*  __restrict__ label,
                                              float* __restrict__ ws) {
    __shared__ int   labS[512];
    __shared__ int   cntS[NC];
    __shared__ float red[256];

    const int tid = threadIdx.x, bid = blockIdx.x;
    const int th = bid & 3, b = bid >> 2;      // t-quarter (512), batch
    const int wave = tid >> 6, lane = tid & 63;
    const int q = lane >> 4, q8 = q * 8, ln16 = lane & 15;
    const int wd0 = wave * 32;                  // this wave's d-range [wd0, wd0+32)

    // ---- stage 512 labels + histogram ----
    if (tid < NC) cntS[tid] = 0;
    __syncthreads();
    {
        const int2 L = *(const int2*)(label + b * NT + th * 512 + tid * 2);
        labS[tid * 2] = L.x; labS[tid * 2 + 1] = L.y;
        atomicAdd(&cntS[L.x], 1); atomicAdd(&cntS[L.y], 1);
    }
    __syncthreads();
    if (tid < NC) ((int*)(ws + OFF_CNTP))[bid * NC + tid] = cntS[tid];

    // ---- K-loop: 16 steps of k=32 (t in [th*512, th*512+512)) ----
    // A frag (feat): lane holds A[m=ln16][k=q8+j] -> d = wd0 + mt*16 + ln16, t = t0k+q8+j
    // B frag (onehot): lane holds B[k=q8+j][n=ln16] -> c = nt*16 + ln16
    // D: row m = q*4+reg (+mt*16), col n = ln16 (+nt*16)
    const float* pA0 = feat + ((size_t)(b * 128 + wd0 + ln16)) * NT + th * 512 + q8;
    const float* pA1 = pA0 + (size_t)16 * NT;

    f32x4 acc[2][4] = {};
    float ss = 0.0f;

    #pragma unroll 2
    for (int ks = 0; ks < 16; ++ks) {
        const int t0k = ks * 32;

        const float4 x0 = *(const float4*)(pA0 + t0k);
        const float4 x1 = *(const float4*)(pA0 + t0k + 4);
        const float4 y0 = *(const float4*)(pA1 + t0k);
        const float4 y1 = *(const float4*)(pA1 + t0k + 4);

        int labv[8];
        #pragma unroll
        for (int j = 0; j < 8; ++j) labv[j] = labS[t0k + q8 + j];

        ss += x0.x * x0.x + x0.y * x0.y + x0.z * x0.z + x0.w * x0.w
            + x1.x * x1.x + x1.y * x1.y + x1.z * x1.z + x1.w * x1.w
            + y0.x * y0.x + y0.y * y0.y + y0.z * y0.z + y0.w * y0.w
            + y1.x * y1.x + y1.y * y1.y + y1.z * y1.z + y1.w * y1.w;

        bf16x8 a0, a1;
        a0[0] = (short)bf16rne(x0.x); a0[1] = (short)bf16rne(x0.y);
        a0[2] = (short)bf16rne(x0.z); a0[3] = (short)bf16rne(x0.w);
        a0[4] = (short)bf16rne(x1.x); a0[5] = (short)bf16rne(x1.y);
        a0[6] = (short)bf16rne(x1.z); a0[7] = (short)bf16rne(x1.w);
        a1[0] = (short)bf16rne(y0.x); a1[1] = (short)bf16rne(y0.y);
        a1[2] = (short)bf16rne(y0.z); a1[3] = (short)bf16rne(y0.w);
        a1[4] = (short)bf16rne(y1.x); a1[5] = (short)bf16rne(y1.y);
        a1[6] = (short)bf16rne(y1.z); a1[7] = (short)bf16rne(y1.w);

        #pragma unroll
        for (int nt = 0; nt < 4; ++nt) {
            const int c_lane = nt * 16 + ln16;
            bf16x8 bo;
            #pragma unroll
            for (int j = 0; j < 8; ++j)
                bo[j] = (labv[j] == c_lane) ? (short)0x3F80 : (short)0;
            acc[0][nt] = __builtin_amdgcn_mfma_f32_16x16x32_bf16(a0, bo, acc[0][nt], 0, 0, 0);
            acc[1][nt] = __builtin_amdgcn_mfma_f32_16x16x32_bf16(a1, bo, acc[1][nt], 0, 0, 0);
        }
    }

    // ---- store partial S tile: P[bid][d][c], d = wd0+mt*16+q*4+r, c = nt*16+ln16 ----
    float* P = ws + OFF_P + (size_t)bid * 8192;
    #pragma unroll
    for (int mt = 0; mt < 2; ++mt)
        #pragma unroll
        for (int nt = 0; nt < 4; ++nt)
            #pragma unroll
            for (int r = 0; r < 4; ++r) {
                const int d = wd0 + mt * 16 + q * 4 + r;
                const int c = nt * 16 + ln16;
                P[d * 64 + c] = acc[mt][nt][r];
            }

    // ---- block sumsq reduce ----
    red[tid] = ss;
    __syncthreads();
    for (int s = 128; s > 0; s >>= 1) {
        if (tid < s) red[tid] += red[tid + s];
        __syncthreads();
    }
    if (tid == 0) ws[OFF_SSP + bid] = red[0];
}

__global__ __launch_bounds__(256) void k_red(float* __restrict__ ws,
                                             const float* __restrict__ centers,
                                             float* __restrict__ out) {
    const int tid = threadIdx.x, bid = blockIdx.x;

    if (bid == 32) {  // sumsq over 512 block partials
        __shared__ float r[256];
        r[tid] = ws[OFF_SSP + tid] + ws[OFF_SSP + 256 + tid];
        __syncthreads();
        for (int k = 128; k > 0; k >>= 1) { if (tid < k) r[tid] += r[tid + k]; __syncthreads(); }
        if (tid == 0) ws[OFF_SS] = r[0];
        return;
    }

    // counts: cnt[c] = sum over 512 blocks
    __shared__ int cred[256];
    __shared__ int cnt[NC];
    {
        const int c = tid & 63, part = tid >> 6;
        const int* cntP = (const int*)(ws + OFF_CNTP);
        int s = 0;
        for (int e2 = part * 128; e2 < part * 128 + 128; ++e2) s += cntP[e2 * NC + c];
        cred[tid] = s;
    }
    __syncthreads();
    if (tid < NC) cnt[tid] = cred[tid] + cred[tid + 64] + cred[tid + 128] + cred[tid + 192];
    __syncthreads();

    // i = (d,c) flat; P reads perfectly coalesced: addr = bb*8192 + i
    const int i = bid * 256 + tid;
    const int d = i >> 6, c = i & 63;
    const float* Pp = ws + OFF_P + i;
    float sum = 0.0f;
    #pragma unroll 8
    for (int bb = 0; bb < 512; ++bb) sum += Pp[(size_t)bb * 8192];

    const float ctr = centers[c * 128 + d];
    const float cn  = (float)cnt[c];
    const float den = cn > 1.0f ? cn : 1.0f;
    out[1 + c * 128 + d] = (cn * ctr - sum) / den;

    __shared__ float r1[256], r2[256];
    r1[tid] = sum * ctr;
    r2[tid] = cn * ctr * ctr;
    __syncthreads();
    for (int k = 128; k > 0; k >>= 1) {
        if (tid < k) { r1[tid] += r1[tid + k]; r2[tid] += r2[tid + k]; }
        __syncthreads();
    }
    if (tid == 0) { ws[OFF_CROSS + bid] = r1[0]; ws[OFF_CC + bid] = r2[0]; }
}

__global__ __launch_bounds__(64) void k_epi(const float* __restrict__ ws,
                                            float* __restrict__ out) {
    int t = threadIdx.x;
    float cr = (t < 32) ? ws[OFF_CROSS + t] : 0.0f;
    float cc = (t < 32) ? ws[OFF_CC + t] : 0.0f;
    for (int o = 16; o > 0; o >>= 1) { cr += __shfl_down(cr, o); cc += __shfl_down(cc, o); }
    if (t == 0) out[0] = (ws[OFF_SS] - 2.0f * cr + cc) * (1.0f / 33554432.0f);
}

extern "C" void kernel_launch(void* const* d_in, const int* in_sizes, int n_in,
                              void* d_out, int out_size, void* d_ws, size_t ws_size,
                              hipStream_t stream) {
    const float* feat    = (const float*)d_in[0];
    const int*   label   = (const int*)d_in[1];
    const float* centers = (const float*)d_in[2];
    float* out = (float*)d_out;
    float* ws  = (float*)d_ws;

    hipLaunchKernelGGL(k_main, dim3(512), dim3(256), 0, stream, feat, label, ws);
    hipLaunchKernelGGL(k_red,  dim3(33),  dim3(256), 0, stream, ws, centers, out);
    hipLaunchKernelGGL(k_epi,  dim3(1),   dim3(64),  0, stream, ws, out);
}

// Round 8
// 220.064 us; speedup vs baseline: 1.1089x; 1.1089x over previous
//
#include <hip/hip_runtime.h>

// CenterLoss: feature [B=128, D=128, T=2048] f32, label [B*T] int32, centers [64,128] f32
// out: [1 + 64*128] f32 = (loss, difference)
//
// R7 one-hot MFMA GEMM worked (absmax 0.0078) but 512x32KB partial tiles (16.8MB)
// + 33-block latency-bound k_red (~0.7TB/s) cost ~30us vs R5.
// R8: 256 k_main blocks (b x t-half) -> 8.4MB partials; k_red with 65 blocks,
// 2 threads/element x 128 tiles each, 16-deep unroll (~1MB in flight).
// K-loop: A = feat straight from global (reg prefetch), B = one-hot in regs. No LDS,
// no barriers, zero atomics (except 1024 histogram adds in prologue).

#define NT 2048
#define NC 64

// ws float offsets
#define OFF_P     0          // [256 blocks][128 d][64 c] partial S (f32)
#define OFF_SSP   2097152    // [256] per-block sumsq
#define OFF_CNTP  2097408    // int [256 blocks][64 c]
#define OFF_CROSS 2113792    // [64]
#define OFF_CC    2113856    // [64]
#define OFF_SS    2113920    // [1]

typedef __attribute__((ext_vector_type(8))) short bf16x8;
typedef __attribute__((ext_vector_type(4))) float f32x4;

__device__ __forceinline__ unsigned short bf16rne(float f) {
    unsigned int u = __float_as_uint(f);
    return (unsigned short)((u + 0x7FFFu + ((u >> 16) & 1u)) >> 16);
}

__global__ __launch_bounds__(256) void k_main(const float* __restrict__ feat,
                                              const int*  __restrict__ label,
                                              float* __restrict__ ws) {
    __shared__ int   labS[1024];
    __shared__ int   cntS[NC];
    __shared__ float red[256];

    const int tid = threadIdx.x, bid = blockIdx.x;
    const int th = bid & 1, b = bid >> 1;      // t-half (1024), batch
    const int wave = tid >> 6, lane = tid & 63;
    const int q = lane >> 4, q8 = q * 8, ln16 = lane & 15;
    const int wd0 = wave * 32;                  // this wave's d-range [wd0, wd0+32)

    // ---- stage 1024 labels + histogram ----
    if (tid < NC) cntS[tid] = 0;
    __syncthreads();
    {
        const int4 L = *(const int4*)(label + b * NT + th * 1024 + tid * 4);
        labS[tid * 4 + 0] = L.x; labS[tid * 4 + 1] = L.y;
        labS[tid * 4 + 2] = L.z; labS[tid * 4 + 3] = L.w;
        atomicAdd(&cntS[L.x], 1); atomicAdd(&cntS[L.y], 1);
        atomicAdd(&cntS[L.z], 1); atomicAdd(&cntS[L.w], 1);
    }
    __syncthreads();
    if (tid < NC) ((int*)(ws + OFF_CNTP))[bid * NC + tid] = cntS[tid];

    // ---- K-loop: 32 steps of k=32 over t in [th*1024, th*1024+1024) ----
    // A frag: lane holds A[m=ln16][k=q8+j] -> d = wd0 + mt*16 + ln16, t = t0k+q8+j
    // B frag: lane holds B[k=q8+j][n=ln16] -> c = nt*16 + ln16
    // D: row m = q*4+reg (+mt*16), col n = ln16 (+nt*16)
    const float* pA0 = feat + ((size_t)(b * 128 + wd0 + ln16)) * NT + th * 1024 + q8;
    const float* pA1 = pA0 + (size_t)16 * NT;

    f32x4 acc[2][4] = {};
    float ss = 0.0f;

    float4 c0 = *(const float4*)(pA0);
    float4 c1 = *(const float4*)(pA0 + 4);
    float4 c2 = *(const float4*)(pA1);
    float4 c3 = *(const float4*)(pA1 + 4);

    #pragma unroll 4
    for (int ks = 0; ks < 32; ++ks) {
        const int t0k = ks * 32;
        float4 n0, n1, n2, n3;
        if (ks < 31) {
            n0 = *(const float4*)(pA0 + t0k + 32);
            n1 = *(const float4*)(pA0 + t0k + 36);
            n2 = *(const float4*)(pA1 + t0k + 32);
            n3 = *(const float4*)(pA1 + t0k + 36);
        }

        const int4 lv0 = *(const int4*)&labS[t0k + q8];
        const int4 lv1 = *(const int4*)&labS[t0k + q8 + 4];

        ss += c0.x * c0.x + c0.y * c0.y + c0.z * c0.z + c0.w * c0.w
            + c1.x * c1.x + c1.y * c1.y + c1.z * c1.z + c1.w * c1.w
            + c2.x * c2.x + c2.y * c2.y + c2.z * c2.z + c2.w * c2.w
            + c3.x * c3.x + c3.y * c3.y + c3.z * c3.z + c3.w * c3.w;

        bf16x8 a0, a1;
        a0[0] = (short)bf16rne(c0.x); a0[1] = (short)bf16rne(c0.y);
        a0[2] = (short)bf16rne(c0.z); a0[3] = (short)bf16rne(c0.w);
        a0[4] = (short)bf16rne(c1.x); a0[5] = (short)bf16rne(c1.y);
        a0[6] = (short)bf16rne(c1.z); a0[7] = (short)bf16rne(c1.w);
        a1[0] = (short)bf16rne(c2.x); a1[1] = (short)bf16rne(c2.y);
        a1[2] = (short)bf16rne(c2.z); a1[3] = (short)bf16rne(c2.w);
        a1[4] = (short)bf16rne(c3.x); a1[5] = (short)bf16rne(c3.y);
        a1[6] = (short)bf16rne(c3.z); a1[7] = (short)bf16rne(c3.w);

        #pragma unroll
        for (int nt = 0; nt < 4; ++nt) {
            const int c_lane = nt * 16 + ln16;
            bf16x8 bo;
            bo[0] = (lv0.x == c_lane) ? (short)0x3F80 : (short)0;
            bo[1] = (lv0.y == c_lane) ? (short)0x3F80 : (short)0;
            bo[2] = (lv0.z == c_lane) ? (short)0x3F80 : (short)0;
            bo[3] = (lv0.w == c_lane) ? (short)0x3F80 : (short)0;
            bo[4] = (lv1.x == c_lane) ? (short)0x3F80 : (short)0;
            bo[5] = (lv1.y == c_lane) ? (short)0x3F80 : (short)0;
            bo[6] = (lv1.z == c_lane) ? (short)0x3F80 : (short)0;
            bo[7] = (lv1.w == c_lane) ? (short)0x3F80 : (short)0;
            acc[0][nt] = __builtin_amdgcn_mfma_f32_16x16x32_bf16(a0, bo, acc[0][nt], 0, 0, 0);
            acc[1][nt] = __builtin_amdgcn_mfma_f32_16x16x32_bf16(a1, bo, acc[1][nt], 0, 0, 0);
        }

        c0 = n0; c1 = n1; c2 = n2; c3 = n3;
    }

    // ---- store partial S tile: P[bid][d][c], d = wd0+mt*16+q*4+r, c = nt*16+ln16 ----
    float* P = ws + OFF_P + (size_t)bid * 8192;
    #pragma unroll
    for (int mt = 0; mt < 2; ++mt)
        #pragma unroll
        for (int nt = 0; nt < 4; ++nt)
            #pragma unroll
            for (int r = 0; r < 4; ++r) {
                const int d = wd0 + mt * 16 + q * 4 + r;
                const int c = nt * 16 + ln16;
                P[d * 64 + c] = acc[mt][nt][r];
            }

    // ---- block sumsq reduce ----
    red[tid] = ss;
    __syncthreads();
    for (int s = 128; s > 0; s >>= 1) {
        if (tid < s) red[tid] += red[tid + s];
        __syncthreads();
    }
    if (tid == 0) ws[OFF_SSP + bid] = red[0];
}

__global__ __launch_bounds__(256) void k_red(float* __restrict__ ws,
                                             const float* __restrict__ centers,
                                             float* __restrict__ out) {
    const int tid = threadIdx.x, bid = blockIdx.x;

    if (bid == 64) {  // sumsq over 256 block partials
        __shared__ float r[256];
        r[tid] = ws[OFF_SSP + tid];
        __syncthreads();
        for (int k = 128; k > 0; k >>= 1) { if (tid < k) r[tid] += r[tid + k]; __syncthreads(); }
        if (tid == 0) ws[OFF_SS] = r[0];
        return;
    }

    // counts: cnt[c] = sum over 256 tiles (redundant per block, ~64KB read)
    __shared__ int cred[256];
    __shared__ int cnt[NC];
    {
        const int c = tid & 63, part = tid >> 6;
        const int* cntP = (const int*)(ws + OFF_CNTP);
        int s = 0;
        #pragma unroll 8
        for (int e2 = part * 64; e2 < part * 64 + 64; ++e2) s += cntP[e2 * NC + c];
        cred[tid] = s;
    }
    __syncthreads();
    if (tid < NC) cnt[tid] = cred[tid] + cred[tid + 64] + cred[tid + 128] + cred[tid + 192];
    __syncthreads();

    // elements: e = bid*128 + (tid&127); two threads split the 256 tiles
    const int el = tid & 127, half = tid >> 7;
    const int e = bid * 128 + el;
    const float* Pp = ws + OFF_P + (size_t)half * 128 * 8192 + e;
    float sum = 0.0f;
    #pragma unroll 16
    for (int bb = 0; bb < 128; ++bb) sum += Pp[(size_t)bb * 8192];

    __shared__ float sh[256];
    sh[tid] = sum;
    __syncthreads();

    __shared__ float r1[256], r2[256];
    float v1 = 0.0f, v2 = 0.0f;
    if (half == 0) {
        const float tot = sh[el] + sh[el + 128];
        const int d = e >> 6, c = e & 63;
        const float ctr = centers[c * 128 + d];
        const float cn  = (float)cnt[c];
        const float den = cn > 1.0f ? cn : 1.0f;
        out[1 + c * 128 + d] = (cn * ctr - tot) / den;
        v1 = tot * ctr;
        v2 = cn * ctr * ctr;
    }
    r1[tid] = v1; r2[tid] = v2;
    __syncthreads();
    for (int k = 128; k > 0; k >>= 1) {
        if (tid < k) { r1[tid] += r1[tid + k]; r2[tid] += r2[tid + k]; }
        __syncthreads();
    }
    if (tid == 0) { ws[OFF_CROSS + bid] = r1[0]; ws[OFF_CC + bid] = r2[0]; }
}

__global__ __launch_bounds__(64) void k_epi(const float* __restrict__ ws,
                                            float* __restrict__ out) {
    int t = threadIdx.x;
    float cr = ws[OFF_CROSS + t];
    float cc = ws[OFF_CC + t];
    #pragma unroll
    for (int o = 32; o > 0; o >>= 1) { cr += __shfl_down(cr, o); cc += __shfl_down(cc, o); }
    if (t == 0) out[0] = (ws[OFF_SS] - 2.0f * cr + cc) * (1.0f / 33554432.0f);
}

extern "C" void kernel_launch(void* const* d_in, const int* in_sizes, int n_in,
                              void* d_out, int out_size, void* d_ws, size_t ws_size,
                              hipStream_t stream) {
    const float* feat    = (const float*)d_in[0];
    const int*   label   = (const int*)d_in[1];
    const float* centers = (const float*)d_in[2];
    float* out = (float*)d_out;
    float* ws  = (float*)d_ws;

    hipLaunchKernelGGL(k_main, dim3(256), dim3(256), 0, stream, feat, label, ws);
    hipLaunchKernelGGL(k_red,  dim3(65),  dim3(256), 0, stream, ws, centers, out);
    hipLaunchKernelGGL(k_epi,  dim3(1),   dim3(64),  0, stream, ws, out);
}